// Round 1
// 523.149 us; speedup vs baseline: 1.0152x; 1.0152x over previous
//
#include <hip/hip_runtime.h>

// Anchor3DHead fused 1x1-conv heads, R3: 2 pixels per lane (float2 x-loads).
// Block = 256 threads = 4 waves; each block covers 128 pixels (lane -> px 2i,2i+1).
// Wave w owns 18 of the 72 output channels over ALL 384 input channels:
//   w0: cls[0..18)   w1: reg[0..18)   w2: reg[18..36)   w3: reg[36..42)+dir[0..12)
// Rationale: R2 was latency-bound (VALUBusy 47%, HBM 14%) -- only 36 FMA-cycles
// per 4B x-load. float2 doubles FMA-per-load to 72 cyc/8B, halving the latency
// coverage a wave must supply. 36 accs + addressing ~= 50 VGPR -> 8 waves/SIMD.
// grid = 1674 blocks = 6.5 blocks/CU demand vs 8 capacity.

constexpr int Bn   = 4;
constexpr int Cc   = 384;
constexpr int Hh   = 248;
constexpr int Ww   = 216;
constexpr int HW   = Hh * Ww;          // 53568 (even -> float2 never straddles batch)
constexpr int NPIX = Bn * HW;          // 214272 = 128 * 1674
constexpr int NCLS = 18;
constexpr int NREG = 42;
constexpr int NDIR = 12;

// One wave's work: NA outputs from weight matrix wA (row stride LDA), plus
// optionally NB outputs from wB (stride LDB), for TWO pixels per lane.
// Weight indices are wave-uniform -> scalar loads (s_load, values in SGPRs).
// x load is one coalesced dwordx2 per lane per channel.
template<int NA, int LDA, int NB, int LDB>
__device__ __forceinline__ void cohort_run2(
    const float* __restrict__ xb,
    const float* __restrict__ wA, const float* __restrict__ bA,
    float* __restrict__ oA,
    const float* __restrict__ wB, const float* __restrict__ bB,
    float* __restrict__ oB)
{
    float a0[NA + NB];   // pixel 2i
    float a1[NA + NB];   // pixel 2i+1
    #pragma unroll
    for (int j = 0; j < NA; ++j) { a0[j] = bA[j]; a1[j] = bA[j]; }
    #pragma unroll
    for (int j = 0; j < NB; ++j) { a0[NA + j] = bB[j]; a1[NA + j] = bB[j]; }

    #pragma unroll 4
    for (int c = 0; c < Cc; ++c) {
        const float2 xv = *reinterpret_cast<const float2*>(xb + (size_t)c * HW);
        #pragma unroll
        for (int j = 0; j < NA; ++j) {
            const float wv = wA[c * LDA + j];
            a0[j] = fmaf(xv.x, wv, a0[j]);
            a1[j] = fmaf(xv.y, wv, a1[j]);
        }
        #pragma unroll
        for (int j = 0; j < NB; ++j) {
            const float wv = wB[c * LDB + j];
            a0[NA + j] = fmaf(xv.x, wv, a0[NA + j]);
            a1[NA + j] = fmaf(xv.y, wv, a1[NA + j]);
        }
    }

    #pragma unroll
    for (int j = 0; j < NA; ++j)
        *reinterpret_cast<float2*>(oA + (size_t)j * HW) = make_float2(a0[j], a1[j]);
    #pragma unroll
    for (int j = 0; j < NB; ++j)
        *reinterpret_cast<float2*>(oB + (size_t)j * HW) = make_float2(a0[NA + j], a1[NA + j]);
}

__global__ __launch_bounds__(256, 8) void head_fused_msplit2(
    const float* __restrict__ x,
    const float* __restrict__ wc, const float* __restrict__ bc,
    const float* __restrict__ wr, const float* __restrict__ br,
    const float* __restrict__ wd, const float* __restrict__ bd,
    float* __restrict__ out)
{
    const int w    = threadIdx.x >> 6;        // wave id 0..3 (uniform per wave)
    const int lane = threadIdx.x & 63;
    const int pix  = blockIdx.x * 128 + lane * 2;  // < 214272 exactly
    const int b    = pix / HW;
    const int p    = pix - b * HW;            // even -> 8B-aligned float2

    const float* __restrict__ xb = x + (size_t)b * Cc * HW + p;

    float* __restrict__ outc = out + (size_t)b * NCLS * HW + p;
    float* __restrict__ outr = out + (size_t)Bn * NCLS * HW
                                   + (size_t)b * NREG * HW + p;
    float* __restrict__ outd = out + (size_t)Bn * (NCLS + NREG) * HW
                                   + (size_t)b * NDIR * HW + p;

    if (w == 0) {
        cohort_run2<18, NCLS, 0, 1>(xb, wc, bc, outc, wc, bc, outc);
    } else if (w == 1) {
        cohort_run2<18, NREG, 0, 1>(xb, wr, br, outr, wr, br, outr);
    } else if (w == 2) {
        cohort_run2<18, NREG, 0, 1>(xb, wr + 18, br + 18, outr + (size_t)18 * HW,
                                    wr, br, outr);
    } else {
        cohort_run2<6, NREG, 12, NDIR>(xb, wr + 36, br + 36, outr + (size_t)36 * HW,
                                       wd, bd, outd);
    }
}

extern "C" void kernel_launch(void* const* d_in, const int* in_sizes, int n_in,
                              void* d_out, int out_size, void* d_ws, size_t ws_size,
                              hipStream_t stream) {
    const float* x  = (const float*)d_in[0];
    const float* wc = (const float*)d_in[1];
    const float* bc = (const float*)d_in[2];
    const float* wr = (const float*)d_in[3];
    const float* br = (const float*)d_in[4];
    const float* wd = (const float*)d_in[5];
    const float* bd = (const float*)d_in[6];
    float* out = (float*)d_out;

    dim3 grid(NPIX / 128);   // 1674 blocks, exact cover (128 pixels per block)
    dim3 block(256);
    head_fused_msplit2<<<grid, block, 0, stream>>>(x, wc, bc, wr, br, wd, bd, out);
}